// Round 2
// baseline (640.271 us; speedup 1.0000x reference)
//
#include <hip/hip_runtime.h>

#define NN 100000
#define EE 1200000
#define ALPHA_C 0.2f
#define EPS_C 1e-5f

// ---------------- CSR build ----------------

__global__ __launch_bounds__(256) void k_zero(int* __restrict__ a, int n) {
  int i = blockIdx.x * 256 + threadIdx.x;
  if (i < n) a[i] = 0;
}

__global__ __launch_bounds__(256) void k_count(const int* __restrict__ dstv, int* __restrict__ deg) {
  int e = blockIdx.x * 256 + threadIdx.x;
  if (e < EE) atomicAdd(&deg[dstv[e]], 1);
}

__global__ __launch_bounds__(256) void k_dinv(const int* __restrict__ deg, float* __restrict__ dinv) {
  int i = blockIdx.x * 256 + threadIdx.x;
  if (i < NN) dinv[i] = rsqrtf((float)deg[i] + 1.0f);  // +1 self-loop
}

__global__ __launch_bounds__(256) void k_scan1(const int* __restrict__ deg, int* __restrict__ rowp,
                                               int* __restrict__ bsum) {
  __shared__ int s[256];
  int t = threadIdx.x;
  int i = blockIdx.x * 256 + t;
  int v = (i < NN) ? deg[i] : 0;
  s[t] = v;
  __syncthreads();
  for (int off = 1; off < 256; off <<= 1) {
    int add = (t >= off) ? s[t - off] : 0;
    __syncthreads();
    s[t] += add;
    __syncthreads();
  }
  if (i < NN) rowp[i] = s[t] - v;           // exclusive
  if (t == 255) bsum[blockIdx.x] = s[255];  // block total
}

__global__ __launch_bounds__(512) void k_scan2(int* __restrict__ bsum, int* __restrict__ rowp, int nb) {
  __shared__ int s[512];
  int t = threadIdx.x;
  int v = (t < nb) ? bsum[t] : 0;
  s[t] = v;
  __syncthreads();
  for (int off = 1; off < 512; off <<= 1) {
    int add = (t >= off) ? s[t - off] : 0;
    __syncthreads();
    s[t] += add;
    __syncthreads();
  }
  if (t < nb) bsum[t] = s[t] - v;
  if (t == 0) rowp[NN] = EE;
}

__global__ __launch_bounds__(256) void k_scan3(int* __restrict__ rowp, const int* __restrict__ bsum) {
  int i = blockIdx.x * 256 + threadIdx.x;
  if (i < NN) rowp[i] += bsum[blockIdx.x];
}

__global__ __launch_bounds__(256) void k_fill(const int* __restrict__ srcv, const int* __restrict__ dstv,
                                              const int* __restrict__ rowp, int* __restrict__ fill,
                                              int* __restrict__ col) {
  int e = blockIdx.x * 256 + threadIdx.x;
  if (e < EE) {
    int d = dstv[e];
    int pos = rowp[d] + atomicAdd(&fill[d], 1);
    col[pos] = srcv[e];
  }
}

// ---------------- SpMM: out[i] = dinv[i]*sum_{s in row i} dinv[s]*feat[s] + dinv[i]^2*feat[i]

__global__ __launch_bounds__(256) void k_spmm(const float* __restrict__ feat, const float* __restrict__ dinv,
                                              const int* __restrict__ rowp, const int* __restrict__ col,
                                              float* __restrict__ outv) {
  int node = blockIdx.x * 4 + (threadIdx.x >> 6);  // one wave per node
  int f = threadIdx.x & 63;                        // lane = feature
  if (node >= NN) return;
  int s = rowp[node], e2 = rowp[node + 1];
  float acc = 0.f;
  for (int j = s; j < e2; ++j) {
    int c = col[j];
    acc += dinv[c] * feat[c * 64 + f];
  }
  float di = dinv[node];
  outv[node * 64 + f] = di * acc + di * di * feat[node * 64 + f];
}

// ---------------- dense helpers ----------------

__device__ __forceinline__ float red16(float v) {
  v += __shfl_xor(v, 1);
  v += __shfl_xor(v, 2);
  v += __shfl_xor(v, 4);
  v += __shfl_xor(v, 8);
  return v;
}

// C[4][4] = At(64x64, transposed [c][n], stride 68) x W(64xWS, [c][f])
template <int WS>
__device__ __forceinline__ void mmk(const float* __restrict__ At, const float* __restrict__ W,
                                    int r0, int c0, float C[4][4]) {
#pragma unroll
  for (int r = 0; r < 4; ++r)
#pragma unroll
    for (int j = 0; j < 4; ++j) C[r][j] = 0.f;
#pragma unroll 4
  for (int c = 0; c < 64; ++c) {
    const float4 a = *(const float4*)(At + c * 68 + r0);
    const float4 w = *(const float4*)(W + c * WS + c0);
    C[0][0] = fmaf(a.x, w.x, C[0][0]); C[0][1] = fmaf(a.x, w.y, C[0][1]);
    C[0][2] = fmaf(a.x, w.z, C[0][2]); C[0][3] = fmaf(a.x, w.w, C[0][3]);
    C[1][0] = fmaf(a.y, w.x, C[1][0]); C[1][1] = fmaf(a.y, w.y, C[1][1]);
    C[1][2] = fmaf(a.y, w.z, C[1][2]); C[1][3] = fmaf(a.y, w.w, C[1][3]);
    C[2][0] = fmaf(a.z, w.x, C[2][0]); C[2][1] = fmaf(a.z, w.y, C[2][1]);
    C[2][2] = fmaf(a.z, w.z, C[2][2]); C[2][3] = fmaf(a.z, w.w, C[2][3]);
    C[3][0] = fmaf(a.w, w.x, C[3][0]); C[3][1] = fmaf(a.w, w.y, C[3][1]);
    C[3][2] = fmaf(a.w, w.z, C[3][2]); C[3][3] = fmaf(a.w, w.w, C[3][3]);
  }
}

__device__ __forceinline__ void ln_rows(float v[4][4]) {
#pragma unroll
  for (int r = 0; r < 4; ++r) {
    float s = v[r][0] + v[r][1] + v[r][2] + v[r][3];
    s = red16(s);
    float mu = s * 0.015625f;
    float q = 0.f;
#pragma unroll
    for (int j = 0; j < 4; ++j) { float d = v[r][j] - mu; q = fmaf(d, d, q); }
    q = red16(q);
    float inv = rsqrtf(q * 0.015625f + EPS_C);
#pragma unroll
    for (int j = 0; j < 4; ++j) v[r][j] = (v[r][j] - mu) * inv;
  }
}

// ---------------- fused per-layer kernel: heads + gate + residual + LN + FF + LN

template <int HAS_H>
__global__ __launch_bounds__(256) void k_layer(
    const float* __restrict__ aggX, const float* __restrict__ aggH,
    const float* __restrict__ h_in, float* __restrict__ h_out,
    const float* __restrict__ Whl, const float* __restrict__ bhl,
    const float* __restrict__ Wxl, const float* __restrict__ bxl,
    const float* __restrict__ gfw, const float* __restrict__ gfb,
    const float* __restrict__ guw, const float* __restrict__ gub,
    const float* __restrict__ ff1w, const float* __restrict__ ff1b,
    const float* __restrict__ ff2w, const float* __restrict__ ff2b) {
  __shared__ float ldsX[64 * 68];
  __shared__ float ldsH[64 * 68];
  __shared__ float ldsW[64 * 64];
  const int t = threadIdx.x;
  const int blk = blockIdx.x;
  const int g = t >> 4, m = t & 15;
  const int r0 = g << 2, c0 = m << 2;

  // stage A tiles transposed [c][n], stride 68
#pragma unroll
  for (int rep = 0; rep < 4; ++rep) {
    int n = rep * 16 + g;
    int gn = blk * 64 + n; if (gn > NN - 1) gn = NN - 1;
    float4 v = *(const float4*)(aggX + gn * 64 + c0);
    ldsX[(c0 + 0) * 68 + n] = v.x; ldsX[(c0 + 1) * 68 + n] = v.y;
    ldsX[(c0 + 2) * 68 + n] = v.z; ldsX[(c0 + 3) * 68 + n] = v.w;
    if (HAS_H) {
      float4 u = *(const float4*)(aggH + gn * 64 + c0);
      ldsH[(c0 + 0) * 68 + n] = u.x; ldsH[(c0 + 1) * 68 + n] = u.y;
      ldsH[(c0 + 2) * 68 + n] = u.z; ldsH[(c0 + 3) * 68 + n] = u.w;
    }
  }

  float gfh[4], gfx4[4], guh[4], gux4[4];
#pragma unroll
  for (int j = 0; j < 4; ++j) {
    gfh[j] = gfw[c0 + j]; gfx4[j] = gfw[64 + c0 + j];
    guh[j] = guw[c0 + j]; gux4[j] = guw[64 + c0 + j];
  }
  const float gfb0 = gfb[0], gub0 = gub[0];

  float acc[4][4];
#pragma unroll
  for (int r = 0; r < 4; ++r)
#pragma unroll
    for (int j = 0; j < 4; ++j) acc[r][j] = 0.f;

  for (int k = 0; k < 4; ++k) {
    __syncthreads();
#pragma unroll
    for (int rep = 0; rep < 4; ++rep) {
      int o = (rep * 256 + t) * 4;
      *(float4*)(ldsW + o) = *(const float4*)(Wxl + k * 4096 + o);
    }
    __syncthreads();
    float Cx[4][4];
    mmk<64>(ldsX, ldsW, r0, c0, Cx);
#pragma unroll
    for (int r = 0; r < 4; ++r)
#pragma unroll
      for (int j = 0; j < 4; ++j) Cx[r][j] += bxl[k * 64 + c0 + j];

    float Ch[4][4];
    if (HAS_H) {
      __syncthreads();
#pragma unroll
      for (int rep = 0; rep < 4; ++rep) {
        int o = (rep * 256 + t) * 4;
        *(float4*)(ldsW + o) = *(const float4*)(Whl + k * 4096 + o);
      }
      __syncthreads();
      mmk<64>(ldsH, ldsW, r0, c0, Ch);
#pragma unroll
      for (int r = 0; r < 4; ++r)
#pragma unroll
        for (int j = 0; j < 4; ++j) Ch[r][j] += bhl[k * 64 + c0 + j];
    } else {
#pragma unroll
      for (int r = 0; r < 4; ++r)
#pragma unroll
        for (int j = 0; j < 4; ++j) Ch[r][j] = bhl[k * 64 + c0 + j];
    }

    // gate: f = a*tanh(<hk,gfw[:64]> + <xk,gfw[64:]> + b); out += (1+f)hk + (1+u)xk
#pragma unroll
    for (int r = 0; r < 4; ++r) {
      float pf = 0.f, pu = 0.f;
#pragma unroll
      for (int j = 0; j < 4; ++j) {
        pf = fmaf(Ch[r][j], gfh[j], pf); pf = fmaf(Cx[r][j], gfx4[j], pf);
        pu = fmaf(Ch[r][j], guh[j], pu); pu = fmaf(Cx[r][j], gux4[j], pu);
      }
      pf = red16(pf); pu = red16(pu);
      float f = ALPHA_C * tanhf(pf + gfb0);
      float u = ALPHA_C * tanhf(pu + gub0);
#pragma unroll
      for (int j = 0; j < 4; ++j)
        acc[r][j] += (1.f + f) * Ch[r][j] + (1.f + u) * Cx[r][j];
    }
  }

  // h = acc/4 + h_old ; LN
  float hmid[4][4];
#pragma unroll
  for (int r = 0; r < 4; ++r) {
    int gn = blk * 64 + r0 + r; if (gn > NN - 1) gn = NN - 1;
    float4 hv;
    if (HAS_H) hv = *(const float4*)(h_in + gn * 64 + c0);
    else { hv.x = 0.f; hv.y = 0.f; hv.z = 0.f; hv.w = 0.f; }
    hmid[r][0] = fmaf(acc[r][0], 0.25f, hv.x);
    hmid[r][1] = fmaf(acc[r][1], 0.25f, hv.y);
    hmid[r][2] = fmaf(acc[r][2], 0.25f, hv.z);
    hmid[r][3] = fmaf(acc[r][3], 0.25f, hv.w);
  }
  ln_rows(hmid);

  // FF: h = LN(relu(h@ff1+b1)@ff2+b2 + h)
  __syncthreads();  // all head-matmul LDS reads done
#pragma unroll
  for (int r = 0; r < 4; ++r)
#pragma unroll
    for (int j = 0; j < 4; ++j) ldsH[(c0 + j) * 68 + (r0 + r)] = hmid[r][j];
#pragma unroll
  for (int rep = 0; rep < 4; ++rep) {
    int o = (rep * 256 + t) * 4;
    *(float4*)(ldsW + o) = *(const float4*)(ff1w + o);
  }
  __syncthreads();
  float F1[4][4];
  mmk<64>(ldsH, ldsW, r0, c0, F1);
#pragma unroll
  for (int r = 0; r < 4; ++r)
#pragma unroll
    for (int j = 0; j < 4; ++j) F1[r][j] = fmaxf(F1[r][j] + ff1b[c0 + j], 0.f);
  __syncthreads();
#pragma unroll
  for (int r = 0; r < 4; ++r)
#pragma unroll
    for (int j = 0; j < 4; ++j) ldsX[(c0 + j) * 68 + (r0 + r)] = F1[r][j];
#pragma unroll
  for (int rep = 0; rep < 4; ++rep) {
    int o = (rep * 256 + t) * 4;
    *(float4*)(ldsW + o) = *(const float4*)(ff2w + o);
  }
  __syncthreads();
  float F2[4][4];
  mmk<64>(ldsX, ldsW, r0, c0, F2);
#pragma unroll
  for (int r = 0; r < 4; ++r)
#pragma unroll
    for (int j = 0; j < 4; ++j) F2[r][j] += ff2b[c0 + j] + hmid[r][j];
  ln_rows(F2);

#pragma unroll
  for (int r = 0; r < 4; ++r) {
    int gn = blk * 64 + r0 + r;
    if (gn < NN) {
      float4 v; v.x = F2[r][0]; v.y = F2[r][1]; v.z = F2[r][2]; v.w = F2[r][3];
      *(float4*)(h_out + gn * 64 + c0) = v;
    }
  }
}

// ---------------- classifier: out = relu(h@w1+b1)@w2+b2

__global__ __launch_bounds__(256) void k_clf(const float* __restrict__ h,
                                             const float* __restrict__ w1, const float* __restrict__ b1,
                                             const float* __restrict__ w2, const float* __restrict__ b2,
                                             float* __restrict__ outv) {
  __shared__ float ldsA[64 * 68];
  __shared__ float ldsW[64 * 64];
  const int t = threadIdx.x;
  const int blk = blockIdx.x;
  const int g = t >> 4, m = t & 15;
  const int r0 = g << 2, c0 = m << 2;

#pragma unroll
  for (int rep = 0; rep < 4; ++rep) {
    int n = rep * 16 + g;
    int gn = blk * 64 + n; if (gn > NN - 1) gn = NN - 1;
    float4 v = *(const float4*)(h + gn * 64 + c0);
    ldsA[(c0 + 0) * 68 + n] = v.x; ldsA[(c0 + 1) * 68 + n] = v.y;
    ldsA[(c0 + 2) * 68 + n] = v.z; ldsA[(c0 + 3) * 68 + n] = v.w;
  }
#pragma unroll
  for (int rep = 0; rep < 4; ++rep) {
    int o = (rep * 256 + t) * 4;
    *(float4*)(ldsW + o) = *(const float4*)(w1 + o);
  }
  __syncthreads();
  float C1[4][4];
  mmk<64>(ldsA, ldsW, r0, c0, C1);
#pragma unroll
  for (int r = 0; r < 4; ++r)
#pragma unroll
    for (int j = 0; j < 4; ++j) C1[r][j] = fmaxf(C1[r][j] + b1[c0 + j], 0.f);
  __syncthreads();
#pragma unroll
  for (int r = 0; r < 4; ++r)
#pragma unroll
    for (int j = 0; j < 4; ++j) ldsA[(c0 + j) * 68 + (r0 + r)] = C1[r][j];
  for (int idx4 = t; idx4 < 640; idx4 += 256) {  // 64*40 floats
    *(float4*)(ldsW + idx4 * 4) = *(const float4*)(w2 + idx4 * 4);
  }
  __syncthreads();
  if (m < 10) {  // only 40 output cols
    float C2[4][4];
    mmk<40>(ldsA, ldsW, r0, c0, C2);
#pragma unroll
    for (int r = 0; r < 4; ++r) {
      int gn = blk * 64 + r0 + r;
      if (gn < NN) {
        float4 v;
        v.x = C2[r][0] + b2[c0 + 0]; v.y = C2[r][1] + b2[c0 + 1];
        v.z = C2[r][2] + b2[c0 + 2]; v.w = C2[r][3] + b2[c0 + 3];
        *(float4*)(outv + gn * 40 + c0) = v;
      }
    }
  }
}

// ---------------- launch ----------------

extern "C" void kernel_launch(void* const* d_in, const int* in_sizes, int n_in,
                              void* d_out, int out_size, void* d_ws, size_t ws_size,
                              hipStream_t stream) {
  (void)in_sizes; (void)n_in; (void)out_size; (void)ws_size;
  const float* x    = (const float*)d_in[0];
  const int*   ei   = (const int*)d_in[1];
  const float* Wh   = (const float*)d_in[2];
  const float* bh   = (const float*)d_in[3];
  const float* Wx   = (const float*)d_in[4];
  const float* bx   = (const float*)d_in[5];
  const float* gfw  = (const float*)d_in[6];
  const float* gfb  = (const float*)d_in[7];
  const float* guw  = (const float*)d_in[8];
  const float* gub  = (const float*)d_in[9];
  const float* ff1w = (const float*)d_in[10];
  const float* ff1b = (const float*)d_in[11];
  const float* ff2w = (const float*)d_in[12];
  const float* ff2b = (const float*)d_in[13];
  const float* c1w  = (const float*)d_in[14];
  const float* c1b  = (const float*)d_in[15];
  const float* c2w  = (const float*)d_in[16];
  const float* c2b  = (const float*)d_in[17];
  float* outv = (float*)d_out;

  char* ws = (char*)d_ws;
  size_t o = 0;
  auto take = [&](size_t b) { char* p = ws + o; o += (b + 255) & ~(size_t)255; return p; };
  int*   deg  = (int*)take((size_t)NN * 4);
  int*   fill = (int*)take((size_t)NN * 4);
  int*   rowp = (int*)take((size_t)(NN + 1) * 4);
  int*   bsum = (int*)take(512 * 4);
  int*   col  = (int*)take((size_t)EE * 4);
  float* dinv = (float*)take((size_t)NN * 4);
  float* aggX = (float*)take((size_t)NN * 64 * 4);
  float* aggH = (float*)take((size_t)NN * 64 * 4);
  float* hbuf = (float*)take((size_t)NN * 64 * 4);

  const int* srcv = ei;
  const int* dstv = ei + EE;

  const int NB_E = (EE + 255) / 256;   // 4688
  const int NB_N = (NN + 255) / 256;   // 391

  k_zero<<<NB_N, 256, 0, stream>>>(deg, NN);
  k_zero<<<NB_N, 256, 0, stream>>>(fill, NN);
  k_count<<<NB_E, 256, 0, stream>>>(dstv, deg);
  k_dinv<<<NB_N, 256, 0, stream>>>(deg, dinv);
  k_scan1<<<NB_N, 256, 0, stream>>>(deg, rowp, bsum);
  k_scan2<<<1, 512, 0, stream>>>(bsum, rowp, NB_N);
  k_scan3<<<NB_N, 256, 0, stream>>>(rowp, bsum);
  k_fill<<<NB_E, 256, 0, stream>>>(srcv, dstv, rowp, fill, col);

  // AggX = norm-aggregate(x)  (shared by both layers)
  k_spmm<<<(NN + 3) / 4, 256, 0, stream>>>(x, dinv, rowp, col, aggX);

  // layer 0 (h=0: hk = bh broadcast)
  k_layer<0><<<(NN + 63) / 64, 256, 0, stream>>>(
      aggX, aggX, hbuf, hbuf,
      Wh, bh, Wx, bx, gfw, gfb, guw, gub,
      ff1w, ff1b, ff2w, ff2b);

  // AggH = norm-aggregate(h1)
  k_spmm<<<(NN + 3) / 4, 256, 0, stream>>>(hbuf, dinv, rowp, col, aggH);

  // layer 1
  k_layer<1><<<(NN + 63) / 64, 256, 0, stream>>>(
      aggX, aggH, hbuf, hbuf,
      Wh + 4 * 4096, bh + 4 * 64, Wx + 4 * 4096, bx + 4 * 64, gfw, gfb, guw, gub,
      ff1w + 4096, ff1b + 64, ff2w + 4096, ff2b + 64);

  // classifier
  k_clf<<<(NN + 63) / 64, 256, 0, stream>>>(hbuf, c1w, c1b, c2w, c2b, outv);
}

// Round 3
// 523.861 us; speedup vs baseline: 1.2222x; 1.2222x over previous
//
#include <hip/hip_runtime.h>

#define NN 100000
#define EE 1200000
#define ALPHA_C 0.2f
#define EPS_C 1e-5f

typedef __attribute__((ext_vector_type(8))) short short8;
typedef __attribute__((ext_vector_type(4))) float f32x4;
#define MFMA __builtin_amdgcn_mfma_f32_16x16x32_bf16

// ---------------- bf16 helpers (round-to-nearest-even-ish split) ----------------

__device__ __forceinline__ ushort f2bf(float f) {
  unsigned u = __float_as_uint(f);
  unsigned r = (u + 0x7FFFu + ((u >> 16) & 1u)) >> 16;
  return (ushort)r;
}
__device__ __forceinline__ float bf2f(ushort h) { return __uint_as_float((unsigned)h << 16); }

// ---------------- CSR build ----------------

__global__ __launch_bounds__(256) void k_zero(int* __restrict__ a, int n) {
  int i = blockIdx.x * 256 + threadIdx.x;
  if (i < n) a[i] = 0;
}

__global__ __launch_bounds__(256) void k_count(const int* __restrict__ dstv, int* __restrict__ deg) {
  int e = blockIdx.x * 256 + threadIdx.x;
  if (e < EE) atomicAdd(&deg[dstv[e]], 1);
}

__global__ __launch_bounds__(256) void k_dinv(const int* __restrict__ deg, float* __restrict__ dinv) {
  int i = blockIdx.x * 256 + threadIdx.x;
  if (i < NN) dinv[i] = rsqrtf((float)deg[i] + 1.0f);  // +1 self-loop
}

__global__ __launch_bounds__(256) void k_scan1(const int* __restrict__ deg, int* __restrict__ rowp,
                                               int* __restrict__ bsum) {
  __shared__ int s[256];
  int t = threadIdx.x;
  int i = blockIdx.x * 256 + t;
  int v = (i < NN) ? deg[i] : 0;
  s[t] = v;
  __syncthreads();
  for (int off = 1; off < 256; off <<= 1) {
    int add = (t >= off) ? s[t - off] : 0;
    __syncthreads();
    s[t] += add;
    __syncthreads();
  }
  if (i < NN) rowp[i] = s[t] - v;
  if (t == 255) bsum[blockIdx.x] = s[255];
}

__global__ __launch_bounds__(512) void k_scan2(int* __restrict__ bsum, int* __restrict__ rowp, int nb) {
  __shared__ int s[512];
  int t = threadIdx.x;
  int v = (t < nb) ? bsum[t] : 0;
  s[t] = v;
  __syncthreads();
  for (int off = 1; off < 512; off <<= 1) {
    int add = (t >= off) ? s[t - off] : 0;
    __syncthreads();
    s[t] += add;
    __syncthreads();
  }
  if (t < nb) bsum[t] = s[t] - v;
  if (t == 0) rowp[NN] = EE;
}

__global__ __launch_bounds__(256) void k_scan3(int* __restrict__ rowp, const int* __restrict__ bsum) {
  int i = blockIdx.x * 256 + threadIdx.x;
  if (i < NN) rowp[i] += bsum[blockIdx.x];
}

__global__ __launch_bounds__(256) void k_fill(const int* __restrict__ srcv, const int* __restrict__ dstv,
                                              const int* __restrict__ rowp, int* __restrict__ fill,
                                              int* __restrict__ col) {
  int e = blockIdx.x * 256 + threadIdx.x;
  if (e < EE) {
    int d = dstv[e];
    int pos = rowp[d] + atomicAdd(&fill[d], 1);
    col[pos] = srcv[e];
  }
}

// ---------------- SpMM ----------------

__global__ __launch_bounds__(256) void k_spmm(const float* __restrict__ feat, const float* __restrict__ dinv,
                                              const int* __restrict__ rowp, const int* __restrict__ col,
                                              float* __restrict__ outv) {
  int node = blockIdx.x * 4 + (threadIdx.x >> 6);
  int f = threadIdx.x & 63;
  if (node >= NN) return;
  int s = rowp[node], e2 = rowp[node + 1];
  float acc = 0.f;
  for (int j = s; j < e2; ++j) {
    int c = col[j];
    acc += dinv[c] * feat[c * 64 + f];
  }
  float di = dinv[node];
  outv[node * 64 + f] = di * acc + di * di * feat[node * 64 + f];
}

// ---------------- weight pre-pack into B-fragment order (hi||lo bf16) ----------------
// For each 64x64 matmul W: frag f = tc*2+kh (tc=col-tile, kh=k-half);
// lane l, j=0..7: value = W[32*kh + 8*(l>>4) + j][16*tc + (l&15)]
// hi at dst[f*512 + l*8 + j], lo at dst[4096 + ...]. 8192 ushort per matmul.
// ids: 0..7 Wx(l*4+k), 8..15 Wh, 16..17 ff1, 18..19 ff2, 20 clf1, 21 clf2(64x40, zero-pad)

__global__ __launch_bounds__(256) void k_pack(const float* __restrict__ Wh, const float* __restrict__ Wx,
                                              const float* __restrict__ ff1w, const float* __restrict__ ff2w,
                                              const float* __restrict__ c1w, const float* __restrict__ c2w,
                                              ushort* __restrict__ wpk) {
  int id = blockIdx.x;
  const float* src;
  int ncol = 64, vcol = 64;
  if (id < 8) src = Wx + id * 4096;
  else if (id < 16) src = Wh + (id - 8) * 4096;
  else if (id < 18) src = ff1w + (id - 16) * 4096;
  else if (id < 20) src = ff2w + (id - 18) * 4096;
  else if (id == 20) src = c1w;
  else { src = c2w; ncol = 40; vcol = 40; }
  ushort* dst = wpk + (size_t)id * 8192;
  for (int p = threadIdx.x; p < 512; p += 256) {
    int f = p >> 6, l = p & 63;
    int kh = f & 1, tc = f >> 1;
    int r0 = 32 * kh + 8 * (l >> 4), c = 16 * tc + (l & 15);
#pragma unroll
    for (int j = 0; j < 8; ++j) {
      float v = (c < vcol) ? src[(r0 + j) * ncol + c] : 0.f;
      ushort h = f2bf(v);
      dst[f * 512 + l * 8 + j] = h;
      dst[4096 + f * 512 + l * 8 + j] = f2bf(v - bf2f(h));
    }
  }
}

// ---------------- dense helpers ----------------

__device__ __forceinline__ float red16(float v) {
  v += __shfl_xor(v, 1);
  v += __shfl_xor(v, 2);
  v += __shfl_xor(v, 4);
  v += __shfl_xor(v, 8);
  return v;
}

// stage a [64 nodes][64 ch] f32 tile into LDS as bf16 hi/lo, pitch 80 (160B rows: b128-clean)
__device__ __forceinline__ void stage_tile(const float* __restrict__ src, int gbase,
                                           ushort* __restrict__ hi, ushort* __restrict__ lo, int t) {
#pragma unroll
  for (int u = 0; u < 4; ++u) {
    int f = u * 256 + t;
    int row = f >> 4, c4 = (f & 15) << 2;
    int gr = gbase + row;
    if (gr > NN - 1) gr = NN - 1;
    float4 v = *(const float4*)(src + gr * 64 + c4);
    ushort h0 = f2bf(v.x), h1 = f2bf(v.y), h2 = f2bf(v.z), h3 = f2bf(v.w);
    ushort l0 = f2bf(v.x - bf2f(h0)), l1 = f2bf(v.y - bf2f(h1)),
           l2 = f2bf(v.z - bf2f(h2)), l3 = f2bf(v.w - bf2f(h3));
    int o = row * 80 + c4;
    *(ushort4*)(hi + o) = make_ushort4(h0, h1, h2, h3);
    *(ushort4*)(lo + o) = make_ushort4(l0, l1, l2, l3);
  }
}

// split-precision MFMA matmul: C[tc] += A(16 rows strip) x W(64 x 16*NT)
// A in LDS hi/lo (pitch 80), W packed frag-order hi||lo.
template <int NT>
__device__ __forceinline__ void mm_mfma(const ushort* __restrict__ Ah, const ushort* __restrict__ Al,
                                        const ushort* __restrict__ wp, int abase, int l, f32x4* C) {
  const short8 a0h = *(const short8*)(Ah + abase);
  const short8 a1h = *(const short8*)(Ah + abase + 32);
  const short8 a0l = *(const short8*)(Al + abase);
  const short8 a1l = *(const short8*)(Al + abase + 32);
#pragma unroll
  for (int tc = 0; tc < NT; ++tc) {
#pragma unroll
    for (int kh = 0; kh < 2; ++kh) {
      const short8 bh = *(const short8*)(wp + (tc * 2 + kh) * 512 + l * 8);
      const short8 bl = *(const short8*)(wp + 4096 + (tc * 2 + kh) * 512 + l * 8);
      const short8 ah = kh ? a1h : a0h;
      const short8 alo = kh ? a1l : a0l;
      C[tc] = MFMA(ah, bh, C[tc], 0, 0, 0);
      C[tc] = MFMA(ah, bl, C[tc], 0, 0, 0);
      C[tc] = MFMA(alo, bh, C[tc], 0, 0, 0);
    }
  }
}

// LN across the 64 cols held as [tc][r] frags by 16 lanes
__device__ __forceinline__ void ln_frag(float v[4][4]) {
#pragma unroll
  for (int r = 0; r < 4; ++r) {
    float s = v[0][r] + v[1][r] + v[2][r] + v[3][r];
    s = red16(s);
    float mu = s * 0.015625f;
    float q = 0.f;
#pragma unroll
    for (int tc = 0; tc < 4; ++tc) { float d = v[tc][r] - mu; q = fmaf(d, d, q); }
    q = red16(q);
    float inv = rsqrtf(q * 0.015625f + EPS_C);
#pragma unroll
    for (int tc = 0; tc < 4; ++tc) v[tc][r] = (v[tc][r] - mu) * inv;
  }
}

// ---------------- fused per-layer kernel (MFMA) ----------------
// 64 nodes/block, 4 waves; wave w owns rows 16w..16w+15 (all 64 cols).
// C/D frag: row = 16w + 4*(l>>4) + r, col = (l&15) + 16*tc.

template <int HAS_H>
__global__ __launch_bounds__(256) void k_layer(
    const float* __restrict__ aggX, const float* __restrict__ aggH,
    const float* __restrict__ h_in, float* __restrict__ h_out,
    const ushort* __restrict__ wxp, const ushort* __restrict__ whp,
    const float* __restrict__ bxl, const float* __restrict__ bhl,
    const float* __restrict__ gfw, const float* __restrict__ gfb,
    const float* __restrict__ guw, const float* __restrict__ gub,
    const ushort* __restrict__ ff1p, const float* __restrict__ ff1b,
    const ushort* __restrict__ ff2p, const float* __restrict__ ff2b) {
  __shared__ ushort aXh[64 * 80], aXl[64 * 80], aYh[64 * 80], aYl[64 * 80];
  const int t = threadIdx.x, blk = blockIdx.x;
  stage_tile(aggX, blk * 64, aXh, aXl, t);
  if (HAS_H) stage_tile(aggH, blk * 64, aYh, aYl, t);
  __syncthreads();

  const int w = t >> 6, l = t & 63, lg = l >> 4, lr = l & 15;
  const int abase = (16 * w + lr) * 80 + 8 * lg;

  float gfhw[4], gfxw[4], guhw[4], guxw[4];
#pragma unroll
  for (int tc = 0; tc < 4; ++tc) {
    gfhw[tc] = gfw[lr + 16 * tc]; gfxw[tc] = gfw[64 + lr + 16 * tc];
    guhw[tc] = guw[lr + 16 * tc]; guxw[tc] = guw[64 + lr + 16 * tc];
  }
  const float gfb0 = gfb[0], gub0 = gub[0];

  float acc[4][4];
#pragma unroll
  for (int tc = 0; tc < 4; ++tc)
#pragma unroll
    for (int r = 0; r < 4; ++r) acc[tc][r] = 0.f;

  for (int k = 0; k < 4; ++k) {
    f32x4 cx[4], ch[4];
#pragma unroll
    for (int tc = 0; tc < 4; ++tc) { cx[tc] = (f32x4)0.f; ch[tc] = (f32x4)0.f; }
    mm_mfma<4>(aXh, aXl, wxp + k * 8192, abase, l, cx);
    if (HAS_H) mm_mfma<4>(aYh, aYl, whp + k * 8192, abase, l, ch);

    float Cx[4][4], Ch[4][4];
#pragma unroll
    for (int tc = 0; tc < 4; ++tc) {
      float bxv = bxl[k * 64 + lr + 16 * tc];
      float bhv = bhl[k * 64 + lr + 16 * tc];
#pragma unroll
      for (int r = 0; r < 4; ++r) {
        Cx[tc][r] = cx[tc][r] + bxv;
        Ch[tc][r] = (HAS_H ? ch[tc][r] : 0.f) + bhv;
      }
    }
#pragma unroll
    for (int r = 0; r < 4; ++r) {
      float pf = 0.f, pu = 0.f;
#pragma unroll
      for (int tc = 0; tc < 4; ++tc) {
        pf = fmaf(Ch[tc][r], gfhw[tc], pf); pf = fmaf(Cx[tc][r], gfxw[tc], pf);
        pu = fmaf(Ch[tc][r], guhw[tc], pu); pu = fmaf(Cx[tc][r], guxw[tc], pu);
      }
      pf = red16(pf); pu = red16(pu);
      float fv = ALPHA_C * tanhf(pf + gfb0);
      float uv = ALPHA_C * tanhf(pu + gub0);
#pragma unroll
      for (int tc = 0; tc < 4; ++tc)
        acc[tc][r] += (1.f + fv) * Ch[tc][r] + (1.f + uv) * Cx[tc][r];
    }
  }

  // hmid = acc/4 + h_in ; LN
  float hmid[4][4];
#pragma unroll
  for (int tc = 0; tc < 4; ++tc)
#pragma unroll
    for (int r = 0; r < 4; ++r) {
      float hv = 0.f;
      if (HAS_H) {
        int gn = blk * 64 + 16 * w + 4 * lg + r;
        if (gn > NN - 1) gn = NN - 1;
        hv = h_in[gn * 64 + lr + 16 * tc];
      }
      hmid[tc][r] = fmaf(acc[tc][r], 0.25f, hv);
    }
  ln_frag(hmid);

  // hmid -> aX (hi/lo) for FF1
  __syncthreads();
#pragma unroll
  for (int tc = 0; tc < 4; ++tc)
#pragma unroll
    for (int r = 0; r < 4; ++r) {
      int o = (16 * w + 4 * lg + r) * 80 + lr + 16 * tc;
      ushort h = f2bf(hmid[tc][r]);
      aXh[o] = h;
      aXl[o] = f2bf(hmid[tc][r] - bf2f(h));
    }
  __syncthreads();

  f32x4 f1[4];
#pragma unroll
  for (int tc = 0; tc < 4; ++tc) f1[tc] = (f32x4)0.f;
  mm_mfma<4>(aXh, aXl, ff1p, abase, l, f1);
  float F1[4][4];
#pragma unroll
  for (int tc = 0; tc < 4; ++tc) {
    float bv = ff1b[lr + 16 * tc];
#pragma unroll
    for (int r = 0; r < 4; ++r) F1[tc][r] = fmaxf(f1[tc][r] + bv, 0.f);
  }
  // F1 -> aY (no barrier needed before: aY reads were fenced above; aX still being read is untouched)
#pragma unroll
  for (int tc = 0; tc < 4; ++tc)
#pragma unroll
    for (int r = 0; r < 4; ++r) {
      int o = (16 * w + 4 * lg + r) * 80 + lr + 16 * tc;
      ushort h = f2bf(F1[tc][r]);
      aYh[o] = h;
      aYl[o] = f2bf(F1[tc][r] - bf2f(h));
    }
  __syncthreads();

  f32x4 f2[4];
#pragma unroll
  for (int tc = 0; tc < 4; ++tc) f2[tc] = (f32x4)0.f;
  mm_mfma<4>(aYh, aYl, ff2p, abase, l, f2);
  float F2[4][4];
#pragma unroll
  for (int tc = 0; tc < 4; ++tc) {
    float bv = ff2b[lr + 16 * tc];
#pragma unroll
    for (int r = 0; r < 4; ++r) F2[tc][r] = f2[tc][r] + bv + hmid[tc][r];
  }
  ln_frag(F2);

#pragma unroll
  for (int tc = 0; tc < 4; ++tc)
#pragma unroll
    for (int r = 0; r < 4; ++r) {
      int gn = blk * 64 + 16 * w + 4 * lg + r;
      if (gn < NN) h_out[gn * 64 + lr + 16 * tc] = F2[tc][r];
    }
}

// ---------------- classifier (MFMA) ----------------

__global__ __launch_bounds__(256) void k_clf(const float* __restrict__ h,
                                             const ushort* __restrict__ c1p, const float* __restrict__ b1,
                                             const ushort* __restrict__ c2p, const float* __restrict__ b2,
                                             float* __restrict__ outv) {
  __shared__ ushort aXh[64 * 80], aXl[64 * 80], aYh[64 * 80], aYl[64 * 80];
  const int t = threadIdx.x, blk = blockIdx.x;
  stage_tile(h, blk * 64, aXh, aXl, t);
  __syncthreads();

  const int w = t >> 6, l = t & 63, lg = l >> 4, lr = l & 15;
  const int abase = (16 * w + lr) * 80 + 8 * lg;

  f32x4 c1[4];
#pragma unroll
  for (int tc = 0; tc < 4; ++tc) c1[tc] = (f32x4)0.f;
  mm_mfma<4>(aXh, aXl, c1p, abase, l, c1);
#pragma unroll
  for (int tc = 0; tc < 4; ++tc) {
    float bv = b1[lr + 16 * tc];
#pragma unroll
    for (int r = 0; r < 4; ++r) {
      float v = fmaxf(c1[tc][r] + bv, 0.f);
      int o = (16 * w + 4 * lg + r) * 80 + lr + 16 * tc;
      ushort hh = f2bf(v);
      aYh[o] = hh;
      aYl[o] = f2bf(v - bf2f(hh));
    }
  }
  __syncthreads();

  f32x4 c2[3];
#pragma unroll
  for (int tc = 0; tc < 3; ++tc) c2[tc] = (f32x4)0.f;
  mm_mfma<3>(aYh, aYl, c2p, abase, l, c2);
#pragma unroll
  for (int tc = 0; tc < 3; ++tc) {
    int cc = lr + 16 * tc;
    if (cc < 40) {
      float bv = b2[cc];
#pragma unroll
      for (int r = 0; r < 4; ++r) {
        int gn = blk * 64 + 16 * w + 4 * lg + r;
        if (gn < NN) outv[gn * 40 + cc] = c2[tc][r] + bv;
      }
    }
  }
}

// ---------------- launch ----------------

extern "C" void kernel_launch(void* const* d_in, const int* in_sizes, int n_in,
                              void* d_out, int out_size, void* d_ws, size_t ws_size,
                              hipStream_t stream) {
  (void)in_sizes; (void)n_in; (void)out_size; (void)ws_size;
  const float* x    = (const float*)d_in[0];
  const int*   ei   = (const int*)d_in[1];
  const float* Wh   = (const float*)d_in[2];
  const float* bh   = (const float*)d_in[3];
  const float* Wx   = (const float*)d_in[4];
  const float* bx   = (const float*)d_in[5];
  const float* gfw  = (const float*)d_in[6];
  const float* gfb  = (const float*)d_in[7];
  const float* guw  = (const float*)d_in[8];
  const float* gub  = (const float*)d_in[9];
  const float* ff1w = (const float*)d_in[10];
  const float* ff1b = (const float*)d_in[11];
  const float* ff2w = (const float*)d_in[12];
  const float* ff2b = (const float*)d_in[13];
  const float* c1w  = (const float*)d_in[14];
  const float* c1b  = (const float*)d_in[15];
  const float* c2w  = (const float*)d_in[16];
  const float* c2b  = (const float*)d_in[17];
  float* outv = (float*)d_out;

  char* ws = (char*)d_ws;
  size_t o = 0;
  auto take = [&](size_t b) { char* p = ws + o; o += (b + 255) & ~(size_t)255; return p; };
  int*    deg  = (int*)take((size_t)NN * 4);
  int*    fill = (int*)take((size_t)NN * 4);
  int*    rowp = (int*)take((size_t)(NN + 1) * 4);
  int*    bsum = (int*)take(512 * 4);
  int*    col  = (int*)take((size_t)EE * 4);
  float*  dinv = (float*)take((size_t)NN * 4);
  ushort* wpk  = (ushort*)take((size_t)22 * 8192 * 2);
  float*  aggX = (float*)take((size_t)NN * 64 * 4);
  float*  aggH = (float*)take((size_t)NN * 64 * 4);
  float*  hbuf = (float*)take((size_t)NN * 64 * 4);

  const int* srcv = ei;
  const int* dstv = ei + EE;

  const int NB_E = (EE + 255) / 256;
  const int NB_N = (NN + 255) / 256;

  k_pack<<<22, 256, 0, stream>>>(Wh, Wx, ff1w, ff2w, c1w, c2w, wpk);
  k_zero<<<NB_N, 256, 0, stream>>>(deg, NN);
  k_zero<<<NB_N, 256, 0, stream>>>(fill, NN);
  k_count<<<NB_E, 256, 0, stream>>>(dstv, deg);
  k_dinv<<<NB_N, 256, 0, stream>>>(deg, dinv);
  k_scan1<<<NB_N, 256, 0, stream>>>(deg, rowp, bsum);
  k_scan2<<<1, 512, 0, stream>>>(bsum, rowp, NB_N);
  k_scan3<<<NB_N, 256, 0, stream>>>(rowp, bsum);
  k_fill<<<NB_E, 256, 0, stream>>>(srcv, dstv, rowp, fill, col);

  k_spmm<<<(NN + 3) / 4, 256, 0, stream>>>(x, dinv, rowp, col, aggX);

  const int NB_L = (NN + 63) / 64;
  // layer 0 (h=0)
  k_layer<0><<<NB_L, 256, 0, stream>>>(
      aggX, aggX, hbuf, hbuf,
      wpk + 0 * 8192, wpk + 8 * 8192, bx, bh, gfw, gfb, guw, gub,
      wpk + 16 * 8192, ff1b, wpk + 18 * 8192, ff2b);

  k_spmm<<<(NN + 3) / 4, 256, 0, stream>>>(hbuf, dinv, rowp, col, aggH);

  // layer 1
  k_layer<1><<<NB_L, 256, 0, stream>>>(
      aggX, aggH, hbuf, hbuf,
      wpk + 4 * 8192, wpk + 12 * 8192, bx + 256, bh + 256, gfw, gfb, guw, gub,
      wpk + 17 * 8192, ff1b + 64, wpk + 19 * 8192, ff2b + 64);

  k_clf<<<NB_L, 256, 0, stream>>>(hbuf, wpk + 20 * 8192, c1b, wpk + 21 * 8192, c2b, outv);
}

// Round 4
// 425.132 us; speedup vs baseline: 1.5061x; 1.2322x over previous
//
#include <hip/hip_runtime.h>

#define NN 100000
#define EE 1200000
#define ALPHA_C 0.2f
#define EPS_C 1e-5f

typedef __attribute__((ext_vector_type(8))) short short8;
typedef __attribute__((ext_vector_type(4))) float f32x4;
#define MFMA __builtin_amdgcn_mfma_f32_16x16x32_bf16

// ---------------- bf16 helpers (round-to-nearest-even-ish split) ----------------

__device__ __forceinline__ ushort f2bf(float f) {
  unsigned u = __float_as_uint(f);
  unsigned r = (u + 0x7FFFu + ((u >> 16) & 1u)) >> 16;
  return (ushort)r;
}
__device__ __forceinline__ float bf2f(ushort h) { return __uint_as_float((unsigned)h << 16); }

// ---------------- CSR build ----------------

__global__ __launch_bounds__(256) void k_zero(int* __restrict__ a, int n) {
  int i = blockIdx.x * 256 + threadIdx.x;
  if (i < n) a[i] = 0;
}

__global__ __launch_bounds__(256) void k_count(const int* __restrict__ dstv, int* __restrict__ deg) {
  int e = blockIdx.x * 256 + threadIdx.x;
  if (e < EE) atomicAdd(&deg[dstv[e]], 1);
}

__global__ __launch_bounds__(256) void k_dinv(const int* __restrict__ deg, float* __restrict__ dinv) {
  int i = blockIdx.x * 256 + threadIdx.x;
  if (i < NN) dinv[i] = rsqrtf((float)deg[i] + 1.0f);  // +1 self-loop
}

__global__ __launch_bounds__(256) void k_scan1(const int* __restrict__ deg, int* __restrict__ rowp,
                                               int* __restrict__ bsum) {
  __shared__ int s[256];
  int t = threadIdx.x;
  int i = blockIdx.x * 256 + t;
  int v = (i < NN) ? deg[i] : 0;
  s[t] = v;
  __syncthreads();
  for (int off = 1; off < 256; off <<= 1) {
    int add = (t >= off) ? s[t - off] : 0;
    __syncthreads();
    s[t] += add;
    __syncthreads();
  }
  if (i < NN) rowp[i] = s[t] - v;
  if (t == 255) bsum[blockIdx.x] = s[255];
}

__global__ __launch_bounds__(512) void k_scan2(int* __restrict__ bsum, int* __restrict__ rowp, int nb) {
  __shared__ int s[512];
  int t = threadIdx.x;
  int v = (t < nb) ? bsum[t] : 0;
  s[t] = v;
  __syncthreads();
  for (int off = 1; off < 512; off <<= 1) {
    int add = (t >= off) ? s[t - off] : 0;
    __syncthreads();
    s[t] += add;
    __syncthreads();
  }
  if (t < nb) bsum[t] = s[t] - v;
  if (t == 0) rowp[NN] = EE;
}

__global__ __launch_bounds__(256) void k_scan3(int* __restrict__ rowp, const int* __restrict__ bsum) {
  int i = blockIdx.x * 256 + threadIdx.x;
  if (i < NN) rowp[i] += bsum[blockIdx.x];
}

__global__ __launch_bounds__(256) void k_fill(const int* __restrict__ srcv, const int* __restrict__ dstv,
                                              const int* __restrict__ rowp, int* __restrict__ fill,
                                              int* __restrict__ col) {
  int e = blockIdx.x * 256 + threadIdx.x;
  if (e < EE) {
    int d = dstv[e];
    int pos = rowp[d] + atomicAdd(&fill[d], 1);
    col[pos] = srcv[e];
  }
}

// ---------------- SpMM (latency-optimized) ----------------

// xs[i*64+f] = dinv[i] * feat[i*64+f]
__global__ __launch_bounds__(256) void k_prescale(const float* __restrict__ feat,
                                                  const float* __restrict__ dinv,
                                                  float* __restrict__ xs) {
  int idx = blockIdx.x * 256 + threadIdx.x;  // float4 index
  if (idx < NN * 16) {
    float4 v = ((const float4*)feat)[idx];
    float d = dinv[idx >> 4];
    v.x *= d; v.y *= d; v.z *= d; v.w *= d;
    ((float4*)xs)[idx] = v;
  }
}

// out[i] = dinv[i] * (sum_{c in row i} xs[c] + xs[i])
__global__ __launch_bounds__(256) void k_spmm(const float* __restrict__ xs, const float* __restrict__ dinv,
                                              const int* __restrict__ rowp, const int* __restrict__ col,
                                              float* __restrict__ outv) {
  int node = blockIdx.x * 4 + (threadIdx.x >> 6);  // one wave per node
  int f = threadIdx.x & 63;                        // lane = feature
  if (node >= NN) return;
  int s = rowp[node], e2 = rowp[node + 1];
  float a0 = 0.f, a1 = 0.f, a2 = 0.f, a3 = 0.f;
  int j = s;
  for (; j + 4 <= e2; j += 4) {
    int c0 = col[j], c1 = col[j + 1], c2 = col[j + 2], c3 = col[j + 3];
    float v0 = xs[c0 * 64 + f];
    float v1 = xs[c1 * 64 + f];
    float v2 = xs[c2 * 64 + f];
    float v3 = xs[c3 * 64 + f];
    a0 += v0; a1 += v1; a2 += v2; a3 += v3;
  }
  for (; j < e2; ++j) a0 += xs[col[j] * 64 + f];
  float di = dinv[node];
  outv[node * 64 + f] = di * (a0 + a1 + a2 + a3 + xs[node * 64 + f]);
}

// ---------------- weight pre-pack into B-fragment order (hi||lo bf16) ----------------
// For each 64x64 matmul W: frag f = tc*2+kh (tc=col-tile, kh=k-half);
// lane l, j=0..7: value = W[32*kh + 8*(l>>4) + j][16*tc + (l&15)]
// hi at dst[f*512 + l*8 + j], lo at dst[4096 + ...]. 8192 ushort per matmul.
// ids: 0..7 Wx(l*4+k), 8..15 Wh, 16..17 ff1, 18..19 ff2, 20 clf1, 21 clf2(64x40, zero-pad)

__global__ __launch_bounds__(256) void k_pack(const float* __restrict__ Wh, const float* __restrict__ Wx,
                                              const float* __restrict__ ff1w, const float* __restrict__ ff2w,
                                              const float* __restrict__ c1w, const float* __restrict__ c2w,
                                              ushort* __restrict__ wpk) {
  int id = blockIdx.x;
  const float* src;
  int ncol = 64, vcol = 64;
  if (id < 8) src = Wx + id * 4096;
  else if (id < 16) src = Wh + (id - 8) * 4096;
  else if (id < 18) src = ff1w + (id - 16) * 4096;
  else if (id < 20) src = ff2w + (id - 18) * 4096;
  else if (id == 20) src = c1w;
  else { src = c2w; ncol = 40; vcol = 40; }
  ushort* dst = wpk + (size_t)id * 8192;
  for (int p = threadIdx.x; p < 512; p += 256) {
    int f = p >> 6, l = p & 63;
    int kh = f & 1, tc = f >> 1;
    int r0 = 32 * kh + 8 * (l >> 4), c = 16 * tc + (l & 15);
#pragma unroll
    for (int j = 0; j < 8; ++j) {
      float v = (c < vcol) ? src[(r0 + j) * ncol + c] : 0.f;
      ushort h = f2bf(v);
      dst[f * 512 + l * 8 + j] = h;
      dst[4096 + f * 512 + l * 8 + j] = f2bf(v - bf2f(h));
    }
  }
}

// ---------------- dense helpers ----------------

__device__ __forceinline__ float red16(float v) {
  v += __shfl_xor(v, 1);
  v += __shfl_xor(v, 2);
  v += __shfl_xor(v, 4);
  v += __shfl_xor(v, 8);
  return v;
}

// stage a [64 nodes][64 ch] f32 tile into LDS as bf16 hi/lo, pitch 80 (160B rows: b128-clean)
__device__ __forceinline__ void stage_tile(const float* __restrict__ src, int gbase,
                                           ushort* __restrict__ hi, ushort* __restrict__ lo, int t) {
#pragma unroll
  for (int u = 0; u < 4; ++u) {
    int f = u * 256 + t;
    int row = f >> 4, c4 = (f & 15) << 2;
    int gr = gbase + row;
    if (gr > NN - 1) gr = NN - 1;
    float4 v = *(const float4*)(src + gr * 64 + c4);
    ushort h0 = f2bf(v.x), h1 = f2bf(v.y), h2 = f2bf(v.z), h3 = f2bf(v.w);
    ushort l0 = f2bf(v.x - bf2f(h0)), l1 = f2bf(v.y - bf2f(h1)),
           l2 = f2bf(v.z - bf2f(h2)), l3 = f2bf(v.w - bf2f(h3));
    int o = row * 80 + c4;
    *(ushort4*)(hi + o) = make_ushort4(h0, h1, h2, h3);
    *(ushort4*)(lo + o) = make_ushort4(l0, l1, l2, l3);
  }
}

// split-precision MFMA matmul: C[tc] += A(16 rows strip) x W(64 x 16*NT)
// A in LDS hi/lo (pitch 80), W packed frag-order hi||lo.
template <int NT>
__device__ __forceinline__ void mm_mfma(const ushort* __restrict__ Ah, const ushort* __restrict__ Al,
                                        const ushort* __restrict__ wp, int abase, int l, f32x4* C) {
  const short8 a0h = *(const short8*)(Ah + abase);
  const short8 a1h = *(const short8*)(Ah + abase + 32);
  const short8 a0l = *(const short8*)(Al + abase);
  const short8 a1l = *(const short8*)(Al + abase + 32);
#pragma unroll
  for (int tc = 0; tc < NT; ++tc) {
#pragma unroll
    for (int kh = 0; kh < 2; ++kh) {
      const short8 bh = *(const short8*)(wp + (tc * 2 + kh) * 512 + l * 8);
      const short8 bl = *(const short8*)(wp + 4096 + (tc * 2 + kh) * 512 + l * 8);
      const short8 ah = kh ? a1h : a0h;
      const short8 alo = kh ? a1l : a0l;
      C[tc] = MFMA(ah, bh, C[tc], 0, 0, 0);
      C[tc] = MFMA(ah, bl, C[tc], 0, 0, 0);
      C[tc] = MFMA(alo, bh, C[tc], 0, 0, 0);
    }
  }
}

// LN across the 64 cols held as [tc][r] frags by 16 lanes
__device__ __forceinline__ void ln_frag(float v[4][4]) {
#pragma unroll
  for (int r = 0; r < 4; ++r) {
    float s = v[0][r] + v[1][r] + v[2][r] + v[3][r];
    s = red16(s);
    float mu = s * 0.015625f;
    float q = 0.f;
#pragma unroll
    for (int tc = 0; tc < 4; ++tc) { float d = v[tc][r] - mu; q = fmaf(d, d, q); }
    q = red16(q);
    float inv = rsqrtf(q * 0.015625f + EPS_C);
#pragma unroll
    for (int tc = 0; tc < 4; ++tc) v[tc][r] = (v[tc][r] - mu) * inv;
  }
}

// ---------------- fused per-layer kernel (MFMA) ----------------
// 64 nodes/block, 4 waves; wave w owns rows 16w..16w+15 (all 64 cols).
// C/D frag: row = 16w + 4*(l>>4) + r, col = (l&15) + 16*tc.

template <int HAS_H>
__global__ __launch_bounds__(256) void k_layer(
    const float* __restrict__ aggX, const float* __restrict__ aggH,
    const float* __restrict__ h_in, float* __restrict__ h_out,
    const ushort* __restrict__ wxp, const ushort* __restrict__ whp,
    const float* __restrict__ bxl, const float* __restrict__ bhl,
    const float* __restrict__ gfw, const float* __restrict__ gfb,
    const float* __restrict__ guw, const float* __restrict__ gub,
    const ushort* __restrict__ ff1p, const float* __restrict__ ff1b,
    const ushort* __restrict__ ff2p, const float* __restrict__ ff2b) {
  __shared__ ushort aXh[64 * 80], aXl[64 * 80], aYh[64 * 80], aYl[64 * 80];
  const int t = threadIdx.x, blk = blockIdx.x;
  stage_tile(aggX, blk * 64, aXh, aXl, t);
  if (HAS_H) stage_tile(aggH, blk * 64, aYh, aYl, t);
  __syncthreads();

  const int w = t >> 6, l = t & 63, lg = l >> 4, lr = l & 15;
  const int abase = (16 * w + lr) * 80 + 8 * lg;

  float gfhw[4], gfxw[4], guhw[4], guxw[4];
#pragma unroll
  for (int tc = 0; tc < 4; ++tc) {
    gfhw[tc] = gfw[lr + 16 * tc]; gfxw[tc] = gfw[64 + lr + 16 * tc];
    guhw[tc] = guw[lr + 16 * tc]; guxw[tc] = guw[64 + lr + 16 * tc];
  }
  const float gfb0 = gfb[0], gub0 = gub[0];

  float acc[4][4];
#pragma unroll
  for (int tc = 0; tc < 4; ++tc)
#pragma unroll
    for (int r = 0; r < 4; ++r) acc[tc][r] = 0.f;

  for (int k = 0; k < 4; ++k) {
    f32x4 cx[4], ch[4];
#pragma unroll
    for (int tc = 0; tc < 4; ++tc) { cx[tc] = (f32x4)0.f; ch[tc] = (f32x4)0.f; }
    mm_mfma<4>(aXh, aXl, wxp + k * 8192, abase, l, cx);
    if (HAS_H) mm_mfma<4>(aYh, aYl, whp + k * 8192, abase, l, ch);

    float Cx[4][4], Ch[4][4];
#pragma unroll
    for (int tc = 0; tc < 4; ++tc) {
      float bxv = bxl[k * 64 + lr + 16 * tc];
      float bhv = bhl[k * 64 + lr + 16 * tc];
#pragma unroll
      for (int r = 0; r < 4; ++r) {
        Cx[tc][r] = cx[tc][r] + bxv;
        Ch[tc][r] = (HAS_H ? ch[tc][r] : 0.f) + bhv;
      }
    }
#pragma unroll
    for (int r = 0; r < 4; ++r) {
      float pf = 0.f, pu = 0.f;
#pragma unroll
      for (int tc = 0; tc < 4; ++tc) {
        pf = fmaf(Ch[tc][r], gfhw[tc], pf); pf = fmaf(Cx[tc][r], gfxw[tc], pf);
        pu = fmaf(Ch[tc][r], guhw[tc], pu); pu = fmaf(Cx[tc][r], guxw[tc], pu);
      }
      pf = red16(pf); pu = red16(pu);
      float fv = ALPHA_C * tanhf(pf + gfb0);
      float uv = ALPHA_C * tanhf(pu + gub0);
#pragma unroll
      for (int tc = 0; tc < 4; ++tc)
        acc[tc][r] += (1.f + fv) * Ch[tc][r] + (1.f + uv) * Cx[tc][r];
    }
  }

  // hmid = acc/4 + h_in ; LN
  float hmid[4][4];
#pragma unroll
  for (int tc = 0; tc < 4; ++tc)
#pragma unroll
    for (int r = 0; r < 4; ++r) {
      float hv = 0.f;
      if (HAS_H) {
        int gn = blk * 64 + 16 * w + 4 * lg + r;
        if (gn > NN - 1) gn = NN - 1;
        hv = h_in[gn * 64 + lr + 16 * tc];
      }
      hmid[tc][r] = fmaf(acc[tc][r], 0.25f, hv);
    }
  ln_frag(hmid);

  // hmid -> aX (hi/lo) for FF1
  __syncthreads();
#pragma unroll
  for (int tc = 0; tc < 4; ++tc)
#pragma unroll
    for (int r = 0; r < 4; ++r) {
      int o = (16 * w + 4 * lg + r) * 80 + lr + 16 * tc;
      ushort h = f2bf(hmid[tc][r]);
      aXh[o] = h;
      aXl[o] = f2bf(hmid[tc][r] - bf2f(h));
    }
  __syncthreads();

  f32x4 f1[4];
#pragma unroll
  for (int tc = 0; tc < 4; ++tc) f1[tc] = (f32x4)0.f;
  mm_mfma<4>(aXh, aXl, ff1p, abase, l, f1);
  float F1[4][4];
#pragma unroll
  for (int tc = 0; tc < 4; ++tc) {
    float bv = ff1b[lr + 16 * tc];
#pragma unroll
    for (int r = 0; r < 4; ++r) F1[tc][r] = fmaxf(f1[tc][r] + bv, 0.f);
  }
  // F1 -> aY
#pragma unroll
  for (int tc = 0; tc < 4; ++tc)
#pragma unroll
    for (int r = 0; r < 4; ++r) {
      int o = (16 * w + 4 * lg + r) * 80 + lr + 16 * tc;
      ushort h = f2bf(F1[tc][r]);
      aYh[o] = h;
      aYl[o] = f2bf(F1[tc][r] - bf2f(h));
    }
  __syncthreads();

  f32x4 f2[4];
#pragma unroll
  for (int tc = 0; tc < 4; ++tc) f2[tc] = (f32x4)0.f;
  mm_mfma<4>(aYh, aYl, ff2p, abase, l, f2);
  float F2[4][4];
#pragma unroll
  for (int tc = 0; tc < 4; ++tc) {
    float bv = ff2b[lr + 16 * tc];
#pragma unroll
    for (int r = 0; r < 4; ++r) F2[tc][r] = f2[tc][r] + bv + hmid[tc][r];
  }
  ln_frag(F2);

#pragma unroll
  for (int tc = 0; tc < 4; ++tc)
#pragma unroll
    for (int r = 0; r < 4; ++r) {
      int gn = blk * 64 + 16 * w + 4 * lg + r;
      if (gn < NN) h_out[gn * 64 + lr + 16 * tc] = F2[tc][r];
    }
}

// ---------------- classifier (MFMA) ----------------

__global__ __launch_bounds__(256) void k_clf(const float* __restrict__ h,
                                             const ushort* __restrict__ c1p, const float* __restrict__ b1,
                                             const ushort* __restrict__ c2p, const float* __restrict__ b2,
                                             float* __restrict__ outv) {
  __shared__ ushort aXh[64 * 80], aXl[64 * 80], aYh[64 * 80], aYl[64 * 80];
  const int t = threadIdx.x, blk = blockIdx.x;
  stage_tile(h, blk * 64, aXh, aXl, t);
  __syncthreads();

  const int w = t >> 6, l = t & 63, lg = l >> 4, lr = l & 15;
  const int abase = (16 * w + lr) * 80 + 8 * lg;

  f32x4 c1[4];
#pragma unroll
  for (int tc = 0; tc < 4; ++tc) c1[tc] = (f32x4)0.f;
  mm_mfma<4>(aXh, aXl, c1p, abase, l, c1);
#pragma unroll
  for (int tc = 0; tc < 4; ++tc) {
    float bv = b1[lr + 16 * tc];
#pragma unroll
    for (int r = 0; r < 4; ++r) {
      float v = fmaxf(c1[tc][r] + bv, 0.f);
      int o = (16 * w + 4 * lg + r) * 80 + lr + 16 * tc;
      ushort hh = f2bf(v);
      aYh[o] = hh;
      aYl[o] = f2bf(v - bf2f(hh));
    }
  }
  __syncthreads();

  f32x4 c2[3];
#pragma unroll
  for (int tc = 0; tc < 3; ++tc) c2[tc] = (f32x4)0.f;
  mm_mfma<3>(aYh, aYl, c2p, abase, l, c2);
#pragma unroll
  for (int tc = 0; tc < 3; ++tc) {
    int cc = lr + 16 * tc;
    if (cc < 40) {
      float bv = b2[cc];
#pragma unroll
      for (int r = 0; r < 4; ++r) {
        int gn = blk * 64 + 16 * w + 4 * lg + r;
        if (gn < NN) outv[gn * 40 + cc] = c2[tc][r] + bv;
      }
    }
  }
}

// ---------------- launch ----------------

extern "C" void kernel_launch(void* const* d_in, const int* in_sizes, int n_in,
                              void* d_out, int out_size, void* d_ws, size_t ws_size,
                              hipStream_t stream) {
  (void)in_sizes; (void)n_in; (void)out_size; (void)ws_size;
  const float* x    = (const float*)d_in[0];
  const int*   ei   = (const int*)d_in[1];
  const float* Wh   = (const float*)d_in[2];
  const float* bh   = (const float*)d_in[3];
  const float* Wx   = (const float*)d_in[4];
  const float* bx   = (const float*)d_in[5];
  const float* gfw  = (const float*)d_in[6];
  const float* gfb  = (const float*)d_in[7];
  const float* guw  = (const float*)d_in[8];
  const float* gub  = (const float*)d_in[9];
  const float* ff1w = (const float*)d_in[10];
  const float* ff1b = (const float*)d_in[11];
  const float* ff2w = (const float*)d_in[12];
  const float* ff2b = (const float*)d_in[13];
  const float* c1w  = (const float*)d_in[14];
  const float* c1b  = (const float*)d_in[15];
  const float* c2w  = (const float*)d_in[16];
  const float* c2b  = (const float*)d_in[17];
  float* outv = (float*)d_out;

  char* ws = (char*)d_ws;
  size_t o = 0;
  auto take = [&](size_t b) { char* p = ws + o; o += (b + 255) & ~(size_t)255; return p; };
  int*    deg  = (int*)take((size_t)NN * 4);
  int*    fill = (int*)take((size_t)NN * 4);
  int*    rowp = (int*)take((size_t)(NN + 1) * 4);
  int*    bsum = (int*)take(512 * 4);
  int*    col  = (int*)take((size_t)EE * 4);
  float*  dinv = (float*)take((size_t)NN * 4);
  ushort* wpk  = (ushort*)take((size_t)22 * 8192 * 2);
  float*  aggX = (float*)take((size_t)NN * 64 * 4);
  float*  aggH = (float*)take((size_t)NN * 64 * 4);
  float*  hbuf = (float*)take((size_t)NN * 64 * 4);
  float*  xsc  = (float*)take((size_t)NN * 64 * 4);

  const int* srcv = ei;
  const int* dstv = ei + EE;

  const int NB_E = (EE + 255) / 256;
  const int NB_N = (NN + 255) / 256;
  const int NB_V4 = (NN * 16 + 255) / 256;  // float4 elements

  k_pack<<<22, 256, 0, stream>>>(Wh, Wx, ff1w, ff2w, c1w, c2w, wpk);
  k_zero<<<NB_N, 256, 0, stream>>>(deg, NN);
  k_zero<<<NB_N, 256, 0, stream>>>(fill, NN);
  k_count<<<NB_E, 256, 0, stream>>>(dstv, deg);
  k_dinv<<<NB_N, 256, 0, stream>>>(deg, dinv);
  k_scan1<<<NB_N, 256, 0, stream>>>(deg, rowp, bsum);
  k_scan2<<<1, 512, 0, stream>>>(bsum, rowp, NB_N);
  k_scan3<<<NB_N, 256, 0, stream>>>(rowp, bsum);
  k_fill<<<NB_E, 256, 0, stream>>>(srcv, dstv, rowp, fill, col);

  // AggX = D^-1/2 (A+I) D^-1/2 x
  k_prescale<<<NB_V4, 256, 0, stream>>>(x, dinv, xsc);
  k_spmm<<<(NN + 3) / 4, 256, 0, stream>>>(xsc, dinv, rowp, col, aggX);

  const int NB_L = (NN + 63) / 64;
  // layer 0 (h=0)
  k_layer<0><<<NB_L, 256, 0, stream>>>(
      aggX, aggX, hbuf, hbuf,
      wpk + 0 * 8192, wpk + 8 * 8192, bx, bh, gfw, gfb, guw, gub,
      wpk + 16 * 8192, ff1b, wpk + 18 * 8192, ff2b);

  // AggH = D^-1/2 (A+I) D^-1/2 h1
  k_prescale<<<NB_V4, 256, 0, stream>>>(hbuf, dinv, xsc);
  k_spmm<<<(NN + 3) / 4, 256, 0, stream>>>(xsc, dinv, rowp, col, aggH);

  // layer 1
  k_layer<1><<<NB_L, 256, 0, stream>>>(
      aggX, aggH, hbuf, hbuf,
      wpk + 4 * 8192, wpk + 12 * 8192, bx + 256, bh + 256, gfw, gfb, guw, gub,
      wpk + 17 * 8192, ff1b + 64, wpk + 19 * 8192, ff2b + 64);

  k_clf<<<NB_L, 256, 0, stream>>>(hbuf, wpk + 20 * 8192, c1b, wpk + 21 * 8192, c2b, outv);
}

// Round 5
// 382.677 us; speedup vs baseline: 1.6731x; 1.1109x over previous
//
#include <hip/hip_runtime.h>

#define NN 100000
#define EE 1200000
#define ALPHA_C 0.2f
#define EPS_C 1e-5f

typedef __attribute__((ext_vector_type(8))) short short8;
typedef __attribute__((ext_vector_type(4))) float f32x4;
#define MFMA __builtin_amdgcn_mfma_f32_16x16x32_bf16

// ---------------- bf16 helpers ----------------

__device__ __forceinline__ ushort f2bf(float f) {
  unsigned u = __float_as_uint(f);
  unsigned r = (u + 0x7FFFu + ((u >> 16) & 1u)) >> 16;
  return (ushort)r;
}
__device__ __forceinline__ float bf2f(ushort h) { return __uint_as_float((unsigned)h << 16); }

// ---------------- CSR build ----------------

__global__ __launch_bounds__(256) void k_zero2(int* __restrict__ a, int* __restrict__ b) {
  int i = blockIdx.x * 256 + threadIdx.x;
  if (i < NN) { a[i] = 0; b[i] = 0; }
}

__global__ __launch_bounds__(256) void k_count(const int* __restrict__ dstv, int* __restrict__ deg) {
  int e = blockIdx.x * 256 + threadIdx.x;
  if (e < EE) atomicAdd(&deg[dstv[e]], 1);
}

__global__ __launch_bounds__(256) void k_scan1(const int* __restrict__ deg, int* __restrict__ rowp,
                                               int* __restrict__ bsum, float* __restrict__ dinv) {
  __shared__ int s[256];
  int t = threadIdx.x;
  int i = blockIdx.x * 256 + t;
  int v = (i < NN) ? deg[i] : 0;
  if (i < NN) dinv[i] = rsqrtf((float)v + 1.0f);  // +1 self-loop
  s[t] = v;
  __syncthreads();
  for (int off = 1; off < 256; off <<= 1) {
    int add = (t >= off) ? s[t - off] : 0;
    __syncthreads();
    s[t] += add;
    __syncthreads();
  }
  if (i < NN) rowp[i] = s[t] - v;
  if (t == 255) bsum[blockIdx.x] = s[255];
}

__global__ __launch_bounds__(512) void k_scan2(int* __restrict__ bsum, int* __restrict__ rowp, int nb) {
  __shared__ int s[512];
  int t = threadIdx.x;
  int v = (t < nb) ? bsum[t] : 0;
  s[t] = v;
  __syncthreads();
  for (int off = 1; off < 512; off <<= 1) {
    int add = (t >= off) ? s[t - off] : 0;
    __syncthreads();
    s[t] += add;
    __syncthreads();
  }
  if (t < nb) bsum[t] = s[t] - v;
  if (t == 0) rowp[NN] = EE;
}

__global__ __launch_bounds__(256) void k_scan3(int* __restrict__ rowp, const int* __restrict__ bsum) {
  int i = blockIdx.x * 256 + threadIdx.x;
  if (i < NN) rowp[i] += bsum[blockIdx.x];
}

__global__ __launch_bounds__(256) void k_fill(const int* __restrict__ srcv, const int* __restrict__ dstv,
                                              const int* __restrict__ rowp, int* __restrict__ fill,
                                              int* __restrict__ col) {
  int e = blockIdx.x * 256 + threadIdx.x;
  if (e < EE) {
    int d = dstv[e];
    int pos = rowp[d] + atomicAdd(&fill[d], 1);
    col[pos] = srcv[e];
  }
}

// ---------------- SpMM ----------------

// xs[i*64+f] = dinv[i] * feat[i*64+f]
__global__ __launch_bounds__(256) void k_prescale(const float* __restrict__ feat,
                                                  const float* __restrict__ dinv,
                                                  float* __restrict__ xs) {
  int idx = blockIdx.x * 256 + threadIdx.x;  // float4 index
  if (idx < NN * 16) {
    float4 v = ((const float4*)feat)[idx];
    float d = dinv[idx >> 4];
    v.x *= d; v.y *= d; v.z *= d; v.w *= d;
    ((float4*)xs)[idx] = v;
  }
}

// out[i] = dinv[i] * (sum_{c in row i} xs[c] + xs[i])
// 16 lanes (float4 each) per node, 16 nodes per 256-thread block; 4-way unrolled gather.
__global__ __launch_bounds__(256) void k_spmm(const float4* __restrict__ xs4, const float* __restrict__ dinv,
                                              const int* __restrict__ rowp, const int* __restrict__ col,
                                              float4* __restrict__ out4) {
  int node = blockIdx.x * 16 + (threadIdx.x >> 4);
  int q = threadIdx.x & 15;
  if (node >= NN) return;
  int s = rowp[node], e = rowp[node + 1];
  float4 a0 = {0.f, 0.f, 0.f, 0.f}, a1 = a0, a2 = a0, a3 = a0;
  int j = s;
  for (; j + 4 <= e; j += 4) {
    int c0 = col[j], c1 = col[j + 1], c2 = col[j + 2], c3 = col[j + 3];
    float4 v0 = xs4[c0 * 16 + q];
    float4 v1 = xs4[c1 * 16 + q];
    float4 v2 = xs4[c2 * 16 + q];
    float4 v3 = xs4[c3 * 16 + q];
    a0 += v0; a1 += v1; a2 += v2; a3 += v3;
  }
  for (; j < e; ++j) a0 += xs4[col[j] * 16 + q];
  float4 sv = xs4[node * 16 + q];
  float d = dinv[node];
  float4 o;
  o.x = d * (a0.x + a1.x + a2.x + a3.x + sv.x);
  o.y = d * (a0.y + a1.y + a2.y + a3.y + sv.y);
  o.z = d * (a0.z + a1.z + a2.z + a3.z + sv.z);
  o.w = d * (a0.w + a1.w + a2.w + a3.w + sv.w);
  out4[node * 16 + q] = o;
}

// ---------------- weight pre-pack (B-fragment order, hi||lo bf16) ----------------
// frag f = tc*2+kh; lane l, j: value = W[32*kh + 8*(l>>4) + j][16*tc + (l&15)]
// ids: 0..7 Wx(l*4+k), 8..15 Wh, 16..17 ff1, 18..19 ff2, 20 clf1, 21 clf2(64x40 pad)

__global__ __launch_bounds__(256) void k_pack(const float* __restrict__ Wh, const float* __restrict__ Wx,
                                              const float* __restrict__ ff1w, const float* __restrict__ ff2w,
                                              const float* __restrict__ c1w, const float* __restrict__ c2w,
                                              ushort* __restrict__ wpk) {
  int id = blockIdx.x;
  const float* src;
  int ncol = 64, vcol = 64;
  if (id < 8) src = Wx + id * 4096;
  else if (id < 16) src = Wh + (id - 8) * 4096;
  else if (id < 18) src = ff1w + (id - 16) * 4096;
  else if (id < 20) src = ff2w + (id - 18) * 4096;
  else if (id == 20) src = c1w;
  else { src = c2w; ncol = 40; vcol = 40; }
  ushort* dst = wpk + (size_t)id * 8192;
  for (int p = threadIdx.x; p < 512; p += 256) {
    int f = p >> 6, l = p & 63;
    int kh = f & 1, tc = f >> 1;
    int r0 = 32 * kh + 8 * (l >> 4), c = 16 * tc + (l & 15);
#pragma unroll
    for (int j = 0; j < 8; ++j) {
      float v = (c < vcol) ? src[(r0 + j) * ncol + c] : 0.f;
      ushort h = f2bf(v);
      dst[f * 512 + l * 8 + j] = h;
      dst[4096 + f * 512 + l * 8 + j] = f2bf(v - bf2f(h));
    }
  }
}

// ---------------- dense helpers ----------------

__device__ __forceinline__ float red16(float v) {
  v += __shfl_xor(v, 1);
  v += __shfl_xor(v, 2);
  v += __shfl_xor(v, 4);
  v += __shfl_xor(v, 8);
  return v;
}

// stage a [64 nodes][64 ch] f32 tile into LDS bf16 hi/lo, pitch 80
__device__ __forceinline__ void stage_tile(const float* __restrict__ src, int gbase,
                                           ushort* __restrict__ hi, ushort* __restrict__ lo, int t) {
#pragma unroll
  for (int u = 0; u < 4; ++u) {
    int f = u * 256 + t;
    int row = f >> 4, c4 = (f & 15) << 2;
    int gr = gbase + row;
    if (gr > NN - 1) gr = NN - 1;
    float4 v = *(const float4*)(src + gr * 64 + c4);
    ushort h0 = f2bf(v.x), h1 = f2bf(v.y), h2 = f2bf(v.z), h3 = f2bf(v.w);
    ushort l0 = f2bf(v.x - bf2f(h0)), l1 = f2bf(v.y - bf2f(h1)),
           l2 = f2bf(v.z - bf2f(h2)), l3 = f2bf(v.w - bf2f(h3));
    int o = row * 80 + c4;
    *(ushort4*)(hi + o) = make_ushort4(h0, h1, h2, h3);
    *(ushort4*)(lo + o) = make_ushort4(l0, l1, l2, l3);
  }
}

// split-precision MFMA from REGISTER A-fragments; B from packed global (hi||lo)
template <int NT>
__device__ __forceinline__ void mm_mfma_r(short8 a0h, short8 a1h, short8 a0l, short8 a1l,
                                          const ushort* __restrict__ wp, int l, f32x4* C) {
#pragma unroll
  for (int tc = 0; tc < NT; ++tc) {
#pragma unroll
    for (int kh = 0; kh < 2; ++kh) {
      const short8 bh = *(const short8*)(wp + (tc * 2 + kh) * 512 + l * 8);
      const short8 bl = *(const short8*)(wp + 4096 + (tc * 2 + kh) * 512 + l * 8);
      const short8 ah = kh ? a1h : a0h;
      const short8 alo = kh ? a1l : a0l;
      C[tc] = MFMA(ah, bh, C[tc], 0, 0, 0);
      C[tc] = MFMA(ah, bl, C[tc], 0, 0, 0);
      C[tc] = MFMA(alo, bh, C[tc], 0, 0, 0);
    }
  }
}

// LN across 64 cols held as [tc][r] frags by 16 lanes
__device__ __forceinline__ void ln_frag(float v[4][4]) {
#pragma unroll
  for (int r = 0; r < 4; ++r) {
    float s = v[0][r] + v[1][r] + v[2][r] + v[3][r];
    s = red16(s);
    float mu = s * 0.015625f;
    float q = 0.f;
#pragma unroll
    for (int tc = 0; tc < 4; ++tc) { float d = v[tc][r] - mu; q = fmaf(d, d, q); }
    q = red16(q);
    float inv = rsqrtf(q * 0.015625f + EPS_C);
#pragma unroll
    for (int tc = 0; tc < 4; ++tc) v[tc][r] = (v[tc][r] - mu) * inv;
  }
}

// ---------------- fused per-layer kernel ----------------
// 64 nodes/block, 4 waves; wave w rows 16w..16w+15. Single LDS tile (20KB), A-frags in regs.
// C/D frag: row = 16w + 4*(l>>4) + r, col = (l&15) + 16*tc.

template <int HAS_H, int WSC>
__global__ __launch_bounds__(256, 4) void k_layer(
    const float* __restrict__ aggX, const float* __restrict__ aggH,
    const float* __restrict__ h_in, float* __restrict__ h_out,
    float* __restrict__ hs_out, const float* __restrict__ dinv,
    const ushort* __restrict__ wxp, const ushort* __restrict__ whp,
    const float* __restrict__ bxl, const float* __restrict__ bhl,
    const float* __restrict__ gfw, const float* __restrict__ gfb,
    const float* __restrict__ guw, const float* __restrict__ gub,
    const ushort* __restrict__ ff1p, const float* __restrict__ ff1b,
    const ushort* __restrict__ ff2p, const float* __restrict__ ff2b) {
  __shared__ ushort th[64 * 80], tl[64 * 80];
  const int t = threadIdx.x, blk = blockIdx.x;
  const int w = t >> 6, l = t & 63, lg = l >> 4, lr = l & 15;
  const int abase = (16 * w + lr) * 80 + 8 * lg;

  stage_tile(aggX, blk * 64, th, tl, t);
  __syncthreads();
  short8 xa0h = *(const short8*)(th + abase);
  short8 xa1h = *(const short8*)(th + abase + 32);
  short8 xa0l = *(const short8*)(tl + abase);
  short8 xa1l = *(const short8*)(tl + abase + 32);
  short8 ha0h = (short8)0, ha1h = (short8)0, ha0l = (short8)0, ha1l = (short8)0;
  if (HAS_H) {
    __syncthreads();  // all X-frag reads done before overwrite
    stage_tile(aggH, blk * 64, th, tl, t);
    __syncthreads();
    ha0h = *(const short8*)(th + abase);
    ha1h = *(const short8*)(th + abase + 32);
    ha0l = *(const short8*)(tl + abase);
    ha1l = *(const short8*)(tl + abase + 32);
  }

  float gfhw[4], gfxw[4], guhw[4], guxw[4];
#pragma unroll
  for (int tc = 0; tc < 4; ++tc) {
    gfhw[tc] = gfw[lr + 16 * tc]; gfxw[tc] = gfw[64 + lr + 16 * tc];
    guhw[tc] = guw[lr + 16 * tc]; guxw[tc] = guw[64 + lr + 16 * tc];
  }
  const float gfb0 = gfb[0], gub0 = gub[0];

  float acc[4][4];
#pragma unroll
  for (int tc = 0; tc < 4; ++tc)
#pragma unroll
    for (int r = 0; r < 4; ++r) acc[tc][r] = 0.f;

  for (int k = 0; k < 4; ++k) {
    f32x4 cx[4], ch[4];
#pragma unroll
    for (int tc = 0; tc < 4; ++tc) { cx[tc] = (f32x4)0.f; ch[tc] = (f32x4)0.f; }
    mm_mfma_r<4>(xa0h, xa1h, xa0l, xa1l, wxp + k * 8192, l, cx);
    if (HAS_H) mm_mfma_r<4>(ha0h, ha1h, ha0l, ha1l, whp + k * 8192, l, ch);

    float Cx[4][4], Ch[4][4];
#pragma unroll
    for (int tc = 0; tc < 4; ++tc) {
      float bxv = bxl[k * 64 + lr + 16 * tc];
      float bhv = bhl[k * 64 + lr + 16 * tc];
#pragma unroll
      for (int r = 0; r < 4; ++r) {
        Cx[tc][r] = cx[tc][r] + bxv;
        Ch[tc][r] = (HAS_H ? ch[tc][r] : 0.f) + bhv;
      }
    }
#pragma unroll
    for (int r = 0; r < 4; ++r) {
      float pf = 0.f, pu = 0.f;
#pragma unroll
      for (int tc = 0; tc < 4; ++tc) {
        pf = fmaf(Ch[tc][r], gfhw[tc], pf); pf = fmaf(Cx[tc][r], gfxw[tc], pf);
        pu = fmaf(Ch[tc][r], guhw[tc], pu); pu = fmaf(Cx[tc][r], guxw[tc], pu);
      }
      pf = red16(pf); pu = red16(pu);
      float fv = ALPHA_C * tanhf(pf + gfb0);
      float uv = ALPHA_C * tanhf(pu + gub0);
#pragma unroll
      for (int tc = 0; tc < 4; ++tc)
        acc[tc][r] += (1.f + fv) * Ch[tc][r] + (1.f + uv) * Cx[tc][r];
    }
  }

  // hmid = acc/4 + h_in ; LN
  float hmid[4][4];
#pragma unroll
  for (int tc = 0; tc < 4; ++tc)
#pragma unroll
    for (int r = 0; r < 4; ++r) {
      float hv = 0.f;
      if (HAS_H) {
        int gn = blk * 64 + 16 * w + 4 * lg + r;
        if (gn > NN - 1) gn = NN - 1;
        hv = h_in[gn * 64 + lr + 16 * tc];
      }
      hmid[tc][r] = fmaf(acc[tc][r], 0.25f, hv);
    }
  ln_frag(hmid);

  __syncthreads();  // all frag reads (X or H) done before reuse
#pragma unroll
  for (int tc = 0; tc < 4; ++tc)
#pragma unroll
    for (int r = 0; r < 4; ++r) {
      int o = (16 * w + 4 * lg + r) * 80 + lr + 16 * tc;
      ushort h = f2bf(hmid[tc][r]);
      th[o] = h;
      tl[o] = f2bf(hmid[tc][r] - bf2f(h));
    }
  __syncthreads();
  short8 m0h = *(const short8*)(th + abase);
  short8 m1h = *(const short8*)(th + abase + 32);
  short8 m0l = *(const short8*)(tl + abase);
  short8 m1l = *(const short8*)(tl + abase + 32);
  __syncthreads();  // all hmid-frag reads done before F1 overwrite

  f32x4 f1[4];
#pragma unroll
  for (int tc = 0; tc < 4; ++tc) f1[tc] = (f32x4)0.f;
  mm_mfma_r<4>(m0h, m1h, m0l, m1l, ff1p, l, f1);
#pragma unroll
  for (int tc = 0; tc < 4; ++tc) {
    float bv = ff1b[lr + 16 * tc];
#pragma unroll
    for (int r = 0; r < 4; ++r) {
      float v = fmaxf(f1[tc][r] + bv, 0.f);
      int o = (16 * w + 4 * lg + r) * 80 + lr + 16 * tc;
      ushort h = f2bf(v);
      th[o] = h;
      tl[o] = f2bf(v - bf2f(h));
    }
  }
  __syncthreads();
  short8 g0h = *(const short8*)(th + abase);
  short8 g1h = *(const short8*)(th + abase + 32);
  short8 g0l = *(const short8*)(tl + abase);
  short8 g1l = *(const short8*)(tl + abase + 32);

  f32x4 f2[4];
#pragma unroll
  for (int tc = 0; tc < 4; ++tc) f2[tc] = (f32x4)0.f;
  mm_mfma_r<4>(g0h, g1h, g0l, g1l, ff2p, l, f2);
  float F2[4][4];
#pragma unroll
  for (int tc = 0; tc < 4; ++tc) {
    float bv = ff2b[lr + 16 * tc];
#pragma unroll
    for (int r = 0; r < 4; ++r) F2[tc][r] = f2[tc][r] + bv + hmid[tc][r];
  }
  ln_frag(F2);

#pragma unroll
  for (int r = 0; r < 4; ++r) {
    int gn = blk * 64 + 16 * w + 4 * lg + r;
    if (gn < NN) {
      float dv = WSC ? dinv[gn] : 0.f;
#pragma unroll
      for (int tc = 0; tc < 4; ++tc) {
        h_out[gn * 64 + lr + 16 * tc] = F2[tc][r];
        if (WSC) hs_out[gn * 64 + lr + 16 * tc] = F2[tc][r] * dv;
      }
    }
  }
}

// ---------------- classifier ----------------

__global__ __launch_bounds__(256) void k_clf(const float* __restrict__ h,
                                             const ushort* __restrict__ c1p, const float* __restrict__ b1,
                                             const ushort* __restrict__ c2p, const float* __restrict__ b2,
                                             float* __restrict__ outv) {
  __shared__ ushort th[64 * 80], tl[64 * 80];
  const int t = threadIdx.x, blk = blockIdx.x;
  const int w = t >> 6, l = t & 63, lg = l >> 4, lr = l & 15;
  const int abase = (16 * w + lr) * 80 + 8 * lg;

  stage_tile(h, blk * 64, th, tl, t);
  __syncthreads();
  short8 a0h = *(const short8*)(th + abase);
  short8 a1h = *(const short8*)(th + abase + 32);
  short8 a0l = *(const short8*)(tl + abase);
  short8 a1l = *(const short8*)(tl + abase + 32);

  f32x4 c1[4];
#pragma unroll
  for (int tc = 0; tc < 4; ++tc) c1[tc] = (f32x4)0.f;
  mm_mfma_r<4>(a0h, a1h, a0l, a1l, c1p, l, c1);
  __syncthreads();  // all frag reads done before overwrite
#pragma unroll
  for (int tc = 0; tc < 4; ++tc) {
    float bv = b1[lr + 16 * tc];
#pragma unroll
    for (int r = 0; r < 4; ++r) {
      float v = fmaxf(c1[tc][r] + bv, 0.f);
      int o = (16 * w + 4 * lg + r) * 80 + lr + 16 * tc;
      ushort hh = f2bf(v);
      th[o] = hh;
      tl[o] = f2bf(v - bf2f(hh));
    }
  }
  __syncthreads();
  short8 m0h = *(const short8*)(th + abase);
  short8 m1h = *(const short8*)(th + abase + 32);
  short8 m0l = *(const short8*)(tl + abase);
  short8 m1l = *(const short8*)(tl + abase + 32);

  f32x4 c2[3];
#pragma unroll
  for (int tc = 0; tc < 3; ++tc) c2[tc] = (f32x4)0.f;
  mm_mfma_r<3>(m0h, m1h, m0l, m1l, c2p, l, c2);
#pragma unroll
  for (int tc = 0; tc < 3; ++tc) {
    int cc = lr + 16 * tc;
    if (cc < 40) {
      float bv = b2[cc];
#pragma unroll
      for (int r = 0; r < 4; ++r) {
        int gn = blk * 64 + 16 * w + 4 * lg + r;
        if (gn < NN) outv[gn * 40 + cc] = c2[tc][r] + bv;
      }
    }
  }
}

// ---------------- launch ----------------

extern "C" void kernel_launch(void* const* d_in, const int* in_sizes, int n_in,
                              void* d_out, int out_size, void* d_ws, size_t ws_size,
                              hipStream_t stream) {
  (void)in_sizes; (void)n_in; (void)out_size; (void)ws_size;
  const float* x    = (const float*)d_in[0];
  const int*   ei   = (const int*)d_in[1];
  const float* Wh   = (const float*)d_in[2];
  const float* bh   = (const float*)d_in[3];
  const float* Wx   = (const float*)d_in[4];
  const float* bx   = (const float*)d_in[5];
  const float* gfw  = (const float*)d_in[6];
  const float* gfb  = (const float*)d_in[7];
  const float* guw  = (const float*)d_in[8];
  const float* gub  = (const float*)d_in[9];
  const float* ff1w = (const float*)d_in[10];
  const float* ff1b = (const float*)d_in[11];
  const float* ff2w = (const float*)d_in[12];
  const float* ff2b = (const float*)d_in[13];
  const float* c1w  = (const float*)d_in[14];
  const float* c1b  = (const float*)d_in[15];
  const float* c2w  = (const float*)d_in[16];
  const float* c2b  = (const float*)d_in[17];
  float* outv = (float*)d_out;

  char* ws = (char*)d_ws;
  size_t o = 0;
  auto take = [&](size_t b) { char* p = ws + o; o += (b + 255) & ~(size_t)255; return p; };
  int*    deg  = (int*)take((size_t)NN * 4);
  int*    fill = (int*)take((size_t)NN * 4);
  int*    rowp = (int*)take((size_t)(NN + 1) * 4);
  int*    bsum = (int*)take(512 * 4);
  int*    col  = (int*)take((size_t)EE * 4);
  float*  dinv = (float*)take((size_t)NN * 4);
  ushort* wpk  = (ushort*)take((size_t)22 * 8192 * 2);
  float*  aggX = (float*)take((size_t)NN * 64 * 4);
  float*  aggH = (float*)take((size_t)NN * 64 * 4);
  float*  hbuf = (float*)take((size_t)NN * 64 * 4);
  float*  xsc  = (float*)take((size_t)NN * 64 * 4);

  const int* srcv = ei;
  const int* dstv = ei + EE;

  const int NB_E = (EE + 255) / 256;
  const int NB_N = (NN + 255) / 256;
  const int NB_V4 = (NN * 16 + 255) / 256;

  k_pack<<<22, 256, 0, stream>>>(Wh, Wx, ff1w, ff2w, c1w, c2w, wpk);
  k_zero2<<<NB_N, 256, 0, stream>>>(deg, fill);
  k_count<<<NB_E, 256, 0, stream>>>(dstv, deg);
  k_scan1<<<NB_N, 256, 0, stream>>>(deg, rowp, bsum, dinv);
  k_scan2<<<1, 512, 0, stream>>>(bsum, rowp, NB_N);
  k_scan3<<<NB_N, 256, 0, stream>>>(rowp, bsum);
  k_fill<<<NB_E, 256, 0, stream>>>(srcv, dstv, rowp, fill, col);

  // AggX
  k_prescale<<<NB_V4, 256, 0, stream>>>(x, dinv, xsc);
  k_spmm<<<(NN + 15) / 16, 256, 0, stream>>>((const float4*)xsc, dinv, rowp, col, (float4*)aggX);

  const int NB_L = (NN + 63) / 64;
  // layer 0 (h=0); writes h1 and h1*dinv (into xsc)
  k_layer<0, 1><<<NB_L, 256, 0, stream>>>(
      aggX, aggX, hbuf, hbuf, xsc, dinv,
      wpk + 0 * 8192, wpk + 8 * 8192, bx, bh, gfw, gfb, guw, gub,
      wpk + 16 * 8192, ff1b, wpk + 18 * 8192, ff2b);

  // AggH
  k_spmm<<<(NN + 15) / 16, 256, 0, stream>>>((const float4*)xsc, dinv, rowp, col, (float4*)aggH);

  // layer 1
  k_layer<1, 0><<<NB_L, 256, 0, stream>>>(
      aggX, aggH, hbuf, hbuf, xsc, dinv,
      wpk + 4 * 8192, wpk + 12 * 8192, bx + 256, bh + 256, gfw, gfb, guw, gub,
      wpk + 17 * 8192, ff1b + 64, wpk + 19 * 8192, ff2b + 64);

  k_clf<<<NB_L, 256, 0, stream>>>(hbuf, wpk + 20 * 8192, c1b, wpk + 21 * 8192, c2b, outv);
}